// Round 7
// baseline (488.567 us; speedup 1.0000x reference)
//
#include <hip/hip_runtime.h>

typedef unsigned short u16;
typedef unsigned int u32;
typedef __attribute__((ext_vector_type(8))) short short8;
typedef __attribute__((ext_vector_type(4))) float f32x4;

// ---------- bf16 helpers (RNE) ----------
__device__ __forceinline__ u16 f2bf(float f) {
    u32 u = __float_as_uint(f);
    u32 r = (u + 0x7fffu + ((u >> 16) & 1u)) >> 16;
    return (u16)r;
}
__device__ __forceinline__ float bf2f(u16 h) {
    return __uint_as_float(((u32)h) << 16);
}

// ---------- async global->LDS, 16B per lane (dst = wave-uniform base + lane*16) ----------
__device__ __forceinline__ void gld16(u16* lds_dst, const u16* g_src) {
    __builtin_amdgcn_global_load_lds(
        (const __attribute__((address_space(1))) unsigned int*)g_src,
        (__attribute__((address_space(3))) unsigned int*)lds_dst,
        16, 0, 0);
}

// =====================================================================
// split_x: fp32 [8192*1024] -> bf16 hi/lo
// =====================================================================
__global__ void split_x_k(const float* __restrict__ x, u16* __restrict__ xh,
                          u16* __restrict__ xl) {
    long i = ((long)blockIdx.x * 256 + threadIdx.x) * 4;
    float4 f = *(const float4*)(x + i);
    u16 h0 = f2bf(f.x), h1 = f2bf(f.y), h2 = f2bf(f.z), h3 = f2bf(f.w);
    u16 l0 = f2bf(f.x - bf2f(h0)), l1 = f2bf(f.y - bf2f(h1));
    u16 l2 = f2bf(f.z - bf2f(h2)), l3 = f2bf(f.w - bf2f(h3));
    uint2 hv, lv;
    hv.x = (u32)h0 | ((u32)h1 << 16); hv.y = (u32)h2 | ((u32)h3 << 16);
    lv.x = (u32)l0 | ((u32)l1 << 16); lv.y = (u32)l2 | ((u32)l3 << 16);
    *(uint2*)(xh + i) = hv;
    *(uint2*)(xl + i) = lv;
}

// =====================================================================
// splitT_w: W[k][n] fp32 (1024x1024, z in 0..2) -> Wt[n][k] bf16 hi/lo
// =====================================================================
__global__ void splitT_w_k(const float* __restrict__ Wq, const float* __restrict__ Wk,
                           const float* __restrict__ Wv, u16* __restrict__ wth,
                           u16* __restrict__ wtl) {
    __shared__ float tile[32][33];
    int z = blockIdx.z;
    const float* W = (z == 0) ? Wq : (z == 1) ? Wk : Wv;
    int n0 = blockIdx.x * 32, k0 = blockIdx.y * 32;
    int tx = threadIdx.x, ty = threadIdx.y;
#pragma unroll
    for (int r0 = 0; r0 < 4; ++r0) {
        int r = ty + r0 * 8;
        tile[r][tx] = W[(long)(k0 + r) * 1024 + n0 + tx];
    }
    __syncthreads();
    long zoff = (long)z * 1024 * 1024;
#pragma unroll
    for (int r0 = 0; r0 < 4; ++r0) {
        int r = ty + r0 * 8;
        float f = tile[tx][r];
        u16 h = f2bf(f), l = f2bf(f - bf2f(h));
        long idx = zoff + (long)(n0 + r) * 1024 + k0 + tx;
        wth[idx] = h;
        wtl[idx] = l;
    }
}

// =====================================================================
// transpose_v: v hi/lo [B*2048][1024] -> vt hi/lo per-batch [1024][2048]
// =====================================================================
__global__ void transpose_v_k(const u16* __restrict__ vh, const u16* __restrict__ vl,
                              u16* __restrict__ vth, u16* __restrict__ vtl) {
    __shared__ u16 th[32][33];
    __shared__ u16 tl[32][33];
    int z = blockIdx.z;
    int d0 = blockIdx.x * 32, s0 = blockIdx.y * 32;
    int tx = threadIdx.x, ty = threadIdx.y;
#pragma unroll
    for (int r0 = 0; r0 < 4; ++r0) {
        int r = ty + r0 * 8;
        long idx = ((long)z * 2048 + s0 + r) * 1024 + d0 + tx;
        th[r][tx] = vh[idx];
        tl[r][tx] = vl[idx];
    }
    __syncthreads();
    long zoff = (long)z * 1024 * 2048;
#pragma unroll
    for (int r0 = 0; r0 < 4; ++r0) {
        int r = ty + r0 * 8;
        long idx = zoff + (long)(d0 + r) * 2048 + s0 + tx;
        vth[idx] = th[tx][r];
        vtl[idx] = tl[tx][r];
    }
}

// =====================================================================
// gemm_k: PROJ ONLY (kept byte-identical to R2/R5 161-us config).
// C = A * B^T, 3-term bf16 hi/lo split. 512 thr = 8 waves, tile 128x256,
// BK=32, ring-3 LDS, depth-2 prefetch, counted vmcnt(6), XOR swizzle.
// =====================================================================
__launch_bounds__(512, 2)
__global__ void gemm_k(const u16* __restrict__ Ah, const u16* __restrict__ Al,
                       const u16* __restrict__ Bh, const u16* __restrict__ Bl,
                       u16* __restrict__ oh0, u16* __restrict__ oh1, u16* __restrict__ oh2,
                       u16* __restrict__ ol0, u16* __restrict__ ol1, u16* __restrict__ ol2,
                       const float* __restrict__ b0, const float* __restrict__ b1,
                       const float* __restrict__ b2) {
    constexpr int NF = 4;
    constexpr int BN = 256;
    constexpr int SLOT = 8192 + NF * 4096;
    __shared__ u16 lds[3 * SLOT];

    const int bi = blockIdx.x, bj = blockIdx.y, z = blockIdx.z;
    const int nsteps = 32;

    const u16* gA_h = Ah;
    const u16* gA_l = Al;
    const u16* gB_h = Bh + (long)z * 1024 * 1024;
    const u16* gB_l = Bl + (long)z * 1024 * 1024;

    const int tid = threadIdx.x;
    const int lane = tid & 63, w = tid >> 6;
    const int wr = w >> 2, wc = w & 3;

    const int srow = tid >> 2;
    const int ls8 = (((tid & 3) ^ ((tid >> 3) & 3)) << 3);
    const long aoff  = ((long)bi * 128 + srow) * 1024 + ls8;
    const long boff0 = ((long)bj * BN + srow) * 1024 + ls8;
    const long boff1 = boff0 + 128L * 1024;
    const int wbase = w * 512;

    f32x4 acc[4][NF] = {};

    const int fr = lane & 15;
    const int ps8 = (((lane >> 4) ^ ((fr >> 1) & 3)) << 3);

    auto stage = [&](int slot, int step) {
        const int k0 = step * 32;
        u16* sb = lds + slot * SLOT;
        gld16(sb + wbase,               gA_h + aoff + k0);
        gld16(sb + 4096 + wbase,        gA_l + aoff + k0);
        gld16(sb + 8192 + wbase,        gB_h + boff0 + k0);
        gld16(sb + 12288 + wbase,       gB_h + boff1 + k0);
        gld16(sb + 16384 + wbase,       gB_l + boff0 + k0);
        gld16(sb + 20480 + wbase,       gB_l + boff1 + k0);
    };

    auto compute = [&](int slot) {
        const u16* LA = lds + slot * SLOT;
        const u16* LB = LA + 8192;
        short8 afh[4], afl[4], bfh[NF], bfl[NF];
#pragma unroll
        for (int m = 0; m < 4; ++m) {
            int off = (wr * 64 + m * 16 + fr) * 32 + ps8;
            afh[m] = *(const short8*)(LA + off);
            afl[m] = *(const short8*)(LA + 4096 + off);
        }
#pragma unroll
        for (int n = 0; n < NF; ++n) {
            int off = (wc * (NF * 16) + n * 16 + fr) * 32 + ps8;
            bfh[n] = *(const short8*)(LB + off);
            bfl[n] = *(const short8*)(LB + NF * 2048 + off);
        }
        __builtin_amdgcn_s_setprio(1);
#pragma unroll
        for (int m = 0; m < 4; ++m)
#pragma unroll
            for (int n = 0; n < NF; ++n) {
                acc[m][n] = __builtin_amdgcn_mfma_f32_16x16x32_bf16(afh[m], bfh[n], acc[m][n], 0, 0, 0);
                acc[m][n] = __builtin_amdgcn_mfma_f32_16x16x32_bf16(afh[m], bfl[n], acc[m][n], 0, 0, 0);
                acc[m][n] = __builtin_amdgcn_mfma_f32_16x16x32_bf16(afl[m], bfh[n], acc[m][n], 0, 0, 0);
            }
        __builtin_amdgcn_s_setprio(0);
    };

    stage(0, 0);
    stage(1, 1);
    int cs = 0, ns = 2;
    for (int h = 0; h < nsteps; ++h) {
        if (h + 1 < nsteps) {
            asm volatile("s_waitcnt vmcnt(6)" ::: "memory");
        } else {
            asm volatile("s_waitcnt vmcnt(0)" ::: "memory");
        }
        __builtin_amdgcn_s_barrier();
        __builtin_amdgcn_sched_barrier(0);
        if (h + 2 < nsteps) stage(ns, h + 2);
        compute(cs);
        cs = (cs == 2) ? 0 : cs + 1;
        ns = (ns == 2) ? 0 : ns + 1;
    }

    const int row0 = bi * 128 + wr * 64 + (lane >> 4) * 4;
    const int col0 = bj * BN + wc * (NF * 16) + (lane & 15);

    const float* bias = (z == 0) ? b0 : (z == 1) ? b1 : b2;
    u16* oh = (z == 0) ? oh0 : (z == 1) ? oh1 : oh2;
    u16* ol = (z == 0) ? ol0 : (z == 1) ? ol1 : ol2;
#pragma unroll
    for (int n = 0; n < NF; ++n) {
        float bv = bias[col0 + n * 16];
#pragma unroll
        for (int m = 0; m < 4; ++m)
#pragma unroll
            for (int j = 0; j < 4; ++j) {
                float v = acc[m][n][j] + bv;
                long idx = (long)(row0 + m * 16 + j) * 1024 + col0 + n * 16;
                u16 h = f2bf(v);
                oh[idx] = h;
                ol[idx] = f2bf(v - bf2f(h));
            }
    }
}

// =====================================================================
// qk_k: S = Q * K^T per batch, causal block-skip. Tile 128x128, ring-2
// LDS (64KB -> 2 blocks/CU), depth-1 prefetch. XCD swizzle (T1) —
// co-resident blocks on one XCD share a bj K-panel (L2 reuse).
// =====================================================================
__launch_bounds__(512, 2)
__global__ void qk_k(const u16* __restrict__ Qh, const u16* __restrict__ Ql,
                     const u16* __restrict__ Kh, const u16* __restrict__ Kl,
                     float* __restrict__ S) {
    constexpr int SLOT = 16384;  // A hi/lo + B hi/lo, each [128][32]
    __shared__ u16 lds[2 * SLOT];

    const int orig = blockIdx.y * 16 + blockIdx.x;       // 0..255
    const int swz = (orig & 7) * 32 + (orig >> 3);       // bijective, 256%8==0
    const int bi = swz & 15, bj = swz >> 4, z = blockIdx.z;
    if (bj > bi) return;
    const int nsteps = 32;

    const u16* gA_h = Qh + (long)z * 2048 * 1024;
    const u16* gA_l = Ql + (long)z * 2048 * 1024;
    const u16* gB_h = Kh + (long)z * 2048 * 1024;
    const u16* gB_l = Kl + (long)z * 2048 * 1024;

    const int tid = threadIdx.x;
    const int lane = tid & 63, w = tid >> 6;
    const int wr = w >> 2, wc = w & 3;

    const int srow = tid >> 2;
    const int ls8 = (((tid & 3) ^ ((tid >> 3) & 3)) << 3);
    const long aoff  = ((long)bi * 128 + srow) * 1024 + ls8;
    const long boff0 = ((long)bj * 128 + srow) * 1024 + ls8;
    const int wbase = w * 512;

    f32x4 acc[4][2] = {};
    const int fr = lane & 15;
    const int ps8 = (((lane >> 4) ^ ((fr >> 1) & 3)) << 3);

    auto stage = [&](int slot, int step) {
        const int k0 = step * 32;
        u16* sb = lds + slot * SLOT;
        gld16(sb + wbase,         gA_h + aoff + k0);
        gld16(sb + 4096 + wbase,  gA_l + aoff + k0);
        gld16(sb + 8192 + wbase,  gB_h + boff0 + k0);
        gld16(sb + 12288 + wbase, gB_l + boff0 + k0);
    };

    auto compute = [&](int slot) {
        const u16* LA = lds + slot * SLOT;
        const u16* LB = LA + 8192;
        short8 afh[4], afl[4], bfh[2], bfl[2];
#pragma unroll
        for (int m = 0; m < 4; ++m) {
            int off = (wr * 64 + m * 16 + fr) * 32 + ps8;
            afh[m] = *(const short8*)(LA + off);
            afl[m] = *(const short8*)(LA + 4096 + off);
        }
#pragma unroll
        for (int n = 0; n < 2; ++n) {
            int off = (wc * 32 + n * 16 + fr) * 32 + ps8;
            bfh[n] = *(const short8*)(LB + off);
            bfl[n] = *(const short8*)(LB + 4096 + off);
        }
        __builtin_amdgcn_s_setprio(1);
#pragma unroll
        for (int m = 0; m < 4; ++m)
#pragma unroll
            for (int n = 0; n < 2; ++n) {
                acc[m][n] = __builtin_amdgcn_mfma_f32_16x16x32_bf16(afh[m], bfh[n], acc[m][n], 0, 0, 0);
                acc[m][n] = __builtin_amdgcn_mfma_f32_16x16x32_bf16(afh[m], bfl[n], acc[m][n], 0, 0, 0);
                acc[m][n] = __builtin_amdgcn_mfma_f32_16x16x32_bf16(afl[m], bfh[n], acc[m][n], 0, 0, 0);
            }
        __builtin_amdgcn_s_setprio(0);
    };

    stage(0, 0);
    int cs = 0;
    for (int h = 0; h < nsteps; ++h) {
        asm volatile("s_waitcnt vmcnt(0)" ::: "memory");
        __builtin_amdgcn_s_barrier();
        __builtin_amdgcn_sched_barrier(0);
        if (h + 1 < nsteps) stage(cs ^ 1, h + 1);
        compute(cs);
        cs ^= 1;
    }

    const int row0 = bi * 128 + wr * 64 + (lane >> 4) * 4;
    const int col0 = bj * 128 + wc * 32 + (lane & 15);
    float* o = S + (long)z * 2048 * 2048;
#pragma unroll
    for (int m = 0; m < 4; ++m)
#pragma unroll
        for (int n = 0; n < 2; ++n)
#pragma unroll
            for (int j = 0; j < 4; ++j)
                o[(long)(row0 + m * 16 + j) * 2048 + col0 + n * 16] = acc[m][n][j];
}

// =====================================================================
// rowred_k: per row i of S: m = max_{j<=i}, inv = 1/sum exp((s-m)/32).
// Writes stats[row] = (m, inv). (Softmax P is materialized on-the-fly
// inside pv_k; numerics bit-identical to the old softmax_k.)
// =====================================================================
__global__ void rowred_k(const float* __restrict__ S, float2* __restrict__ stats) {
    const long row = blockIdx.x;  // 0..8191
    const int i = (int)(row & 2047);
    const float* srow = S + row * 2048;
    const int t = threadIdx.x;

    float v[8];
    float m = -1e30f;
#pragma unroll
    for (int j = 0; j < 8; ++j) {
        int c = j * 256 + t;
        float x = (c <= i) ? srow[c] : -1e30f;
        v[j] = x;
        m = fmaxf(m, x);
    }
#pragma unroll
    for (int off = 32; off; off >>= 1) m = fmaxf(m, __shfl_xor(m, off));
    __shared__ float redm[4], reds[4];
    if ((t & 63) == 0) redm[t >> 6] = m;
    __syncthreads();
    m = fmaxf(fmaxf(redm[0], redm[1]), fmaxf(redm[2], redm[3]));

    float s = 0.f;
#pragma unroll
    for (int j = 0; j < 8; ++j) {
        int c = j * 256 + t;
        float e = (c <= i) ? __expf((v[j] - m) * 0.03125f) : 0.f;
        s += e;
    }
#pragma unroll
    for (int off = 32; off; off >>= 1) s += __shfl_xor(s, off);
    if ((t & 63) == 0) reds[t >> 6] = s;
    __syncthreads();
    s = reds[0] + reds[1] + reds[2] + reds[3];
    if (t == 0) stats[row] = make_float2(m, 1.f / s);
}

// =====================================================================
// pv_k: out = softmax(S) * V per batch. Tile 128x128, K limited to the
// causal diagonal, bi launch-reversed (LPT). A-side (P) is produced
// ON-THE-FLY: reg-load S fp32 (32B/thread), p = exp((s-m)/32)*inv with
// causal mask (bit-identical to old softmax_k), hi/lo split in-register,
// ds_write_b128 into the same swizzled LDS slots gld16 would fill.
// B-side (Vt) staged via gld16. Ring-2, 1 barrier/step.
// =====================================================================
__launch_bounds__(512, 2)
__global__ void pv_k(const float* __restrict__ S, const float2* __restrict__ stats,
                     const u16* __restrict__ Vth, const u16* __restrict__ Vtl,
                     float* __restrict__ out) {
    constexpr int SLOT = 16384;
    __shared__ u16 lds[2 * SLOT];

    const int bi = 15 - (int)blockIdx.x;  // LPT: longest K first
    const int bj = blockIdx.y, z = blockIdx.z;
    const int nsteps = (bi + 1) * 4;

    const float* gS = S + (long)z * 2048 * 2048;
    const float2* gst = stats + (long)z * 2048;
    const u16* gB_h = Vth + (long)z * 1024 * 2048;
    const u16* gB_l = Vtl + (long)z * 1024 * 2048;

    const int tid = threadIdx.x;
    const int lane = tid & 63, w = tid >> 6;
    const int wr = w >> 2, wc = w & 3;

    const int srow = tid >> 2;
    const int ls8 = (((tid & 3) ^ ((tid >> 3) & 3)) << 3);
    const int arow = bi * 128 + srow;        // local S row this thread stages
    const long arowoff = (long)arow * 2048;
    const long boff0 = ((long)bj * 128 + srow) * 2048 + ls8;
    const int wbase = w * 512;

    const float2 st = gst[arow];
    const float mrow = st.x, inv = st.y;

    f32x4 acc[4][2] = {};
    const int fr = lane & 15;
    const int ps8 = (((lane >> 4) ^ ((fr >> 1) & 3)) << 3);

    float4 sv0, sv1;  // staged 8 fp32 S elems

    auto loadS = [&](int step) {
        const float* p = gS + arowoff + step * 32 + ls8;
        sv0 = *(const float4*)p;
        sv1 = *(const float4*)(p + 4);
    };
    auto stageV = [&](int slot, int step) {
        u16* sb = lds + slot * SLOT;
        gld16(sb + 8192 + wbase,  gB_h + boff0 + step * 32);
        gld16(sb + 12288 + wbase, gB_l + boff0 + step * 32);
    };
    auto writeP = [&](int slot, int step) {
        const int c0 = step * 32 + ls8;
        float sf[8] = {sv0.x, sv0.y, sv0.z, sv0.w, sv1.x, sv1.y, sv1.z, sv1.w};
        u16 h8[8], l8[8];
#pragma unroll
        for (int e = 0; e < 8; ++e) {
            float p = ((c0 + e) <= arow) ? __expf((sf[e] - mrow) * 0.03125f) * inv : 0.f;
            u16 h = f2bf(p);
            h8[e] = h;
            l8[e] = f2bf(p - bf2f(h));
        }
        u16* sb = lds + slot * SLOT;
        *(short8*)(sb + wbase + lane * 8)        = *(const short8*)h8;
        *(short8*)(sb + 4096 + wbase + lane * 8) = *(const short8*)l8;
    };
    auto compute = [&](int slot) {
        const u16* LA = lds + slot * SLOT;
        const u16* LB = LA + 8192;
        short8 afh[4], afl[4], bfh[2], bfl[2];
#pragma unroll
        for (int m = 0; m < 4; ++m) {
            int off = (wr * 64 + m * 16 + fr) * 32 + ps8;
            afh[m] = *(const short8*)(LA + off);
            afl[m] = *(const short8*)(LA + 4096 + off);
        }
#pragma unroll
        for (int n = 0; n < 2; ++n) {
            int off = (wc * 32 + n * 16 + fr) * 32 + ps8;
            bfh[n] = *(const short8*)(LB + off);
            bfl[n] = *(const short8*)(LB + 4096 + off);
        }
        __builtin_amdgcn_s_setprio(1);
#pragma unroll
        for (int m = 0; m < 4; ++m)
#pragma unroll
            for (int n = 0; n < 2; ++n) {
                acc[m][n] = __builtin_amdgcn_mfma_f32_16x16x32_bf16(afh[m], bfh[n], acc[m][n], 0, 0, 0);
                acc[m][n] = __builtin_amdgcn_mfma_f32_16x16x32_bf16(afh[m], bfl[n], acc[m][n], 0, 0, 0);
                acc[m][n] = __builtin_amdgcn_mfma_f32_16x16x32_bf16(afl[m], bfh[n], acc[m][n], 0, 0, 0);
            }
        __builtin_amdgcn_s_setprio(0);
    };

    // prologue: fill slot 0 (V via gld16, P via reg->exp->ds_write)
    loadS(0);
    stageV(0, 0);
    asm volatile("s_waitcnt vmcnt(0)" ::: "memory");
    writeP(0, 0);
    asm volatile("s_waitcnt lgkmcnt(0)" ::: "memory");
    __builtin_amdgcn_s_barrier();
    __builtin_amdgcn_sched_barrier(0);

    int cs = 0;
    for (int h = 0; h < nsteps; ++h) {
        if (h + 1 < nsteps) { loadS(h + 1); stageV(cs ^ 1, h + 1); }
        compute(cs);
        if (h + 1 < nsteps) {
            asm volatile("s_waitcnt vmcnt(0)" ::: "memory");  // S regs + V gld16 landed
            writeP(cs ^ 1, h + 1);
            asm volatile("s_waitcnt lgkmcnt(0)" ::: "memory");  // ds_writes retired
        }
        __builtin_amdgcn_s_barrier();
        __builtin_amdgcn_sched_barrier(0);
        cs ^= 1;
    }

    const int row0 = bi * 128 + wr * 64 + (lane >> 4) * 4;
    const int col0 = bj * 128 + wc * 32 + (lane & 15);
    float* o = out + (long)z * 2048 * 1024;
#pragma unroll
    for (int m = 0; m < 4; ++m)
#pragma unroll
        for (int n = 0; n < 2; ++n)
#pragma unroll
            for (int j = 0; j < 4; ++j)
                o[(long)(row0 + m * 16 + j) * 1024 + col0 + n * 16] = acc[m][n][j];
}

// =====================================================================
extern "C" void kernel_launch(void* const* d_in, const int* in_sizes, int n_in,
                              void* d_out, int out_size, void* d_ws, size_t ws_size,
                              hipStream_t stream) {
    const float* x  = (const float*)d_in[0];
    const float* Wq = (const float*)d_in[1];
    const float* bq = (const float*)d_in[2];
    const float* Wk = (const float*)d_in[3];
    const float* bk = (const float*)d_in[4];
    const float* Wv = (const float*)d_in[5];
    const float* bv = (const float*)d_in[6];
    float* out = (float*)d_out;
    char* ws = (char*)d_ws;
    const size_t MB = 1ull << 20;

    // region1 (64MB): [xs_hi xs_lo wt_hi wt_lo] during proj, then S
    u16* xs_hi = (u16*)(ws + 0 * MB);
    u16* xs_lo = (u16*)(ws + 16 * MB);
    u16* wt_hi = (u16*)(ws + 32 * MB);
    u16* wt_lo = (u16*)(ws + 38 * MB);
    float* S   = (float*)(ws + 0 * MB);      // 64MB, after proj complete
    // region2: [q_hi q_lo k_hi k_lo] during qk; stats after qk completes
    u16* q_hi = (u16*)(ws + 64 * MB);
    u16* q_lo = (u16*)(ws + 80 * MB);
    u16* k_hi = (u16*)(ws + 96 * MB);
    u16* k_lo = (u16*)(ws + 112 * MB);
    float2* stats = (float2*)(ws + 64 * MB);  // 64KB, after qk complete
    // region3/4
    u16* v_hi  = (u16*)(ws + 128 * MB);
    u16* v_lo  = (u16*)(ws + 144 * MB);
    u16* vt_hi = (u16*)(ws + 160 * MB);
    u16* vt_lo = (u16*)(ws + 176 * MB);

    // 1) split x into bf16 hi/lo
    split_x_k<<<8192, 256, 0, stream>>>(x, xs_hi, xs_lo);
    // 2) transpose+split W -> Wt hi/lo ([3][1024][1024])
    splitT_w_k<<<dim3(32, 32, 3), dim3(32, 8), 0, stream>>>(Wq, Wk, Wv, wt_hi, wt_lo);
    // 3) QKV projections (128x256 tiles, R2-proven 161us config)
    gemm_k<<<dim3(64, 4, 3), 512, 0, stream>>>(
        xs_hi, xs_lo, wt_hi, wt_lo, q_hi, k_hi, v_hi, q_lo, k_lo, v_lo, bq, bk, bv);
    // 4) transpose V per batch -> vt [1024][2048]
    transpose_v_k<<<dim3(32, 64, 4), dim3(32, 8), 0, stream>>>(v_hi, v_lo, vt_hi, vt_lo);
    // 5) scores S = Q*K^T, causal block-skip, XCD-swizzled
    qk_k<<<dim3(16, 16, 4), 512, 0, stream>>>(q_hi, q_lo, k_hi, k_lo, S);
    // 6) per-row (max, 1/sum) stats
    rowred_k<<<8192, 256, 0, stream>>>(S, stats);
    // 7) out = softmax(S)*V with on-the-fly P, K-limited, LPT order
    pv_k<<<dim3(16, 8, 4), 512, 0, stream>>>(S, stats, vt_hi, vt_lo, out);
}

// Round 8
// 460.202 us; speedup vs baseline: 1.0616x; 1.0616x over previous
//
#include <hip/hip_runtime.h>

typedef unsigned short u16;
typedef unsigned int u32;
typedef __attribute__((ext_vector_type(8))) short short8;
typedef __attribute__((ext_vector_type(4))) float f32x4;

// ---------- bf16 helpers (RNE) ----------
__device__ __forceinline__ u16 f2bf(float f) {
    u32 u = __float_as_uint(f);
    u32 r = (u + 0x7fffu + ((u >> 16) & 1u)) >> 16;
    return (u16)r;
}
__device__ __forceinline__ float bf2f(u16 h) {
    return __uint_as_float(((u32)h) << 16);
}

// ---------- async global->LDS, 16B per lane (dst = wave-uniform base + lane*16) ----------
__device__ __forceinline__ void gld16(u16* lds_dst, const u16* g_src) {
    __builtin_amdgcn_global_load_lds(
        (const __attribute__((address_space(1))) unsigned int*)g_src,
        (__attribute__((address_space(3))) unsigned int*)lds_dst,
        16, 0, 0);
}

// =====================================================================
// split_x: fp32 [8192*1024] -> bf16 hi/lo
// =====================================================================
__global__ void split_x_k(const float* __restrict__ x, u16* __restrict__ xh,
                          u16* __restrict__ xl) {
    long i = ((long)blockIdx.x * 256 + threadIdx.x) * 4;
    float4 f = *(const float4*)(x + i);
    u16 h0 = f2bf(f.x), h1 = f2bf(f.y), h2 = f2bf(f.z), h3 = f2bf(f.w);
    u16 l0 = f2bf(f.x - bf2f(h0)), l1 = f2bf(f.y - bf2f(h1));
    u16 l2 = f2bf(f.z - bf2f(h2)), l3 = f2bf(f.w - bf2f(h3));
    uint2 hv, lv;
    hv.x = (u32)h0 | ((u32)h1 << 16); hv.y = (u32)h2 | ((u32)h3 << 16);
    lv.x = (u32)l0 | ((u32)l1 << 16); lv.y = (u32)l2 | ((u32)l3 << 16);
    *(uint2*)(xh + i) = hv;
    *(uint2*)(xl + i) = lv;
}

// =====================================================================
// splitT_w: W[k][n] fp32 (1024x1024, z in 0..2) -> Wt[n][k] bf16 hi/lo
// =====================================================================
__global__ void splitT_w_k(const float* __restrict__ Wq, const float* __restrict__ Wk,
                           const float* __restrict__ Wv, u16* __restrict__ wth,
                           u16* __restrict__ wtl) {
    __shared__ float tile[32][33];
    int z = blockIdx.z;
    const float* W = (z == 0) ? Wq : (z == 1) ? Wk : Wv;
    int n0 = blockIdx.x * 32, k0 = blockIdx.y * 32;
    int tx = threadIdx.x, ty = threadIdx.y;
#pragma unroll
    for (int r0 = 0; r0 < 4; ++r0) {
        int r = ty + r0 * 8;
        tile[r][tx] = W[(long)(k0 + r) * 1024 + n0 + tx];
    }
    __syncthreads();
    long zoff = (long)z * 1024 * 1024;
#pragma unroll
    for (int r0 = 0; r0 < 4; ++r0) {
        int r = ty + r0 * 8;
        float f = tile[tx][r];
        u16 h = f2bf(f), l = f2bf(f - bf2f(h));
        long idx = zoff + (long)(n0 + r) * 1024 + k0 + tx;
        wth[idx] = h;
        wtl[idx] = l;
    }
}

// =====================================================================
// transpose_v: v hi/lo [B*2048][1024] -> vt hi/lo per-batch [1024][2048]
// =====================================================================
__global__ void transpose_v_k(const u16* __restrict__ vh, const u16* __restrict__ vl,
                              u16* __restrict__ vth, u16* __restrict__ vtl) {
    __shared__ u16 th[32][33];
    __shared__ u16 tl[32][33];
    int z = blockIdx.z;
    int d0 = blockIdx.x * 32, s0 = blockIdx.y * 32;
    int tx = threadIdx.x, ty = threadIdx.y;
#pragma unroll
    for (int r0 = 0; r0 < 4; ++r0) {
        int r = ty + r0 * 8;
        long idx = ((long)z * 2048 + s0 + r) * 1024 + d0 + tx;
        th[r][tx] = vh[idx];
        tl[r][tx] = vl[idx];
    }
    __syncthreads();
    long zoff = (long)z * 1024 * 2048;
#pragma unroll
    for (int r0 = 0; r0 < 4; ++r0) {
        int r = ty + r0 * 8;
        long idx = zoff + (long)(d0 + r) * 2048 + s0 + tx;
        vth[idx] = th[tx][r];
        vtl[idx] = tl[tx][r];
    }
}

// =====================================================================
// proj_k: ONE projection (q, k, or v — pointers passed per launch).
// Body/schedule byte-identical to the R2/R5 161-us proj config:
// C = A*B^T 3-term split, 8 waves, tile 128x256, BK=32, ring-3 LDS,
// depth-2 prefetch, counted vmcnt(6), XOR swizzle. Grid (64,4).
// Split into 3 dispatches (~55us each) so qk_k/pv_k surface in top-5.
// =====================================================================
__launch_bounds__(512, 2)
__global__ void proj_k(const u16* __restrict__ Ah, const u16* __restrict__ Al,
                       const u16* __restrict__ Bh, const u16* __restrict__ Bl,
                       u16* __restrict__ oh, u16* __restrict__ ol,
                       const float* __restrict__ bias) {
    constexpr int NF = 4;
    constexpr int BN = 256;
    constexpr int SLOT = 8192 + NF * 4096;
    __shared__ u16 lds[3 * SLOT];

    const int bi = blockIdx.x, bj = blockIdx.y;
    const int nsteps = 32;

    const int tid = threadIdx.x;
    const int lane = tid & 63, w = tid >> 6;
    const int wr = w >> 2, wc = w & 3;

    const int srow = tid >> 2;
    const int ls8 = (((tid & 3) ^ ((tid >> 3) & 3)) << 3);
    const long aoff  = ((long)bi * 128 + srow) * 1024 + ls8;
    const long boff0 = ((long)bj * BN + srow) * 1024 + ls8;
    const long boff1 = boff0 + 128L * 1024;
    const int wbase = w * 512;

    f32x4 acc[4][NF] = {};

    const int fr = lane & 15;
    const int ps8 = (((lane >> 4) ^ ((fr >> 1) & 3)) << 3);

    auto stage = [&](int slot, int step) {
        const int k0 = step * 32;
        u16* sb = lds + slot * SLOT;
        gld16(sb + wbase,               Ah + aoff + k0);
        gld16(sb + 4096 + wbase,        Al + aoff + k0);
        gld16(sb + 8192 + wbase,        Bh + boff0 + k0);
        gld16(sb + 12288 + wbase,       Bh + boff1 + k0);
        gld16(sb + 16384 + wbase,       Bl + boff0 + k0);
        gld16(sb + 20480 + wbase,       Bl + boff1 + k0);
    };

    auto compute = [&](int slot) {
        const u16* LA = lds + slot * SLOT;
        const u16* LB = LA + 8192;
        short8 afh[4], afl[4], bfh[NF], bfl[NF];
#pragma unroll
        for (int m = 0; m < 4; ++m) {
            int off = (wr * 64 + m * 16 + fr) * 32 + ps8;
            afh[m] = *(const short8*)(LA + off);
            afl[m] = *(const short8*)(LA + 4096 + off);
        }
#pragma unroll
        for (int n = 0; n < NF; ++n) {
            int off = (wc * (NF * 16) + n * 16 + fr) * 32 + ps8;
            bfh[n] = *(const short8*)(LB + off);
            bfl[n] = *(const short8*)(LB + NF * 2048 + off);
        }
        __builtin_amdgcn_s_setprio(1);
#pragma unroll
        for (int m = 0; m < 4; ++m)
#pragma unroll
            for (int n = 0; n < NF; ++n) {
                acc[m][n] = __builtin_amdgcn_mfma_f32_16x16x32_bf16(afh[m], bfh[n], acc[m][n], 0, 0, 0);
                acc[m][n] = __builtin_amdgcn_mfma_f32_16x16x32_bf16(afh[m], bfl[n], acc[m][n], 0, 0, 0);
                acc[m][n] = __builtin_amdgcn_mfma_f32_16x16x32_bf16(afl[m], bfh[n], acc[m][n], 0, 0, 0);
            }
        __builtin_amdgcn_s_setprio(0);
    };

    stage(0, 0);
    stage(1, 1);
    int cs = 0, ns = 2;
    for (int h = 0; h < nsteps; ++h) {
        if (h + 1 < nsteps) {
            asm volatile("s_waitcnt vmcnt(6)" ::: "memory");
        } else {
            asm volatile("s_waitcnt vmcnt(0)" ::: "memory");
        }
        __builtin_amdgcn_s_barrier();
        __builtin_amdgcn_sched_barrier(0);
        if (h + 2 < nsteps) stage(ns, h + 2);
        compute(cs);
        cs = (cs == 2) ? 0 : cs + 1;
        ns = (ns == 2) ? 0 : ns + 1;
    }

    const int row0 = bi * 128 + wr * 64 + (lane >> 4) * 4;
    const int col0 = bj * BN + wc * (NF * 16) + (lane & 15);
#pragma unroll
    for (int n = 0; n < NF; ++n) {
        float bv = bias[col0 + n * 16];
#pragma unroll
        for (int m = 0; m < 4; ++m)
#pragma unroll
            for (int j = 0; j < 4; ++j) {
                float v = acc[m][n][j] + bv;
                long idx = (long)(row0 + m * 16 + j) * 1024 + col0 + n * 16;
                u16 h = f2bf(v);
                oh[idx] = h;
                ol[idx] = f2bf(v - bf2f(h));
            }
    }
}

// =====================================================================
// qk_k: S = Q * K^T per batch, causal block-skip. Tile 128x128, ring-2
// LDS (64KB -> 2 blocks/CU), depth-1 prefetch. R5-exact (no swizzle).
// =====================================================================
__launch_bounds__(512, 2)
__global__ void qk_k(const u16* __restrict__ Qh, const u16* __restrict__ Ql,
                     const u16* __restrict__ Kh, const u16* __restrict__ Kl,
                     float* __restrict__ S) {
    constexpr int SLOT = 16384;  // A hi/lo + B hi/lo, each [128][32]
    __shared__ u16 lds[2 * SLOT];

    const int bi = blockIdx.x, bj = blockIdx.y, z = blockIdx.z;
    if (bj > bi) return;
    const int nsteps = 32;

    const u16* gA_h = Qh + (long)z * 2048 * 1024;
    const u16* gA_l = Ql + (long)z * 2048 * 1024;
    const u16* gB_h = Kh + (long)z * 2048 * 1024;
    const u16* gB_l = Kl + (long)z * 2048 * 1024;

    const int tid = threadIdx.x;
    const int lane = tid & 63, w = tid >> 6;
    const int wr = w >> 2, wc = w & 3;

    const int srow = tid >> 2;
    const int ls8 = (((tid & 3) ^ ((tid >> 3) & 3)) << 3);
    const long aoff  = ((long)bi * 128 + srow) * 1024 + ls8;
    const long boff0 = ((long)bj * 128 + srow) * 1024 + ls8;
    const int wbase = w * 512;

    f32x4 acc[4][2] = {};
    const int fr = lane & 15;
    const int ps8 = (((lane >> 4) ^ ((fr >> 1) & 3)) << 3);

    auto stage = [&](int slot, int step) {
        const int k0 = step * 32;
        u16* sb = lds + slot * SLOT;
        gld16(sb + wbase,         gA_h + aoff + k0);
        gld16(sb + 4096 + wbase,  gA_l + aoff + k0);
        gld16(sb + 8192 + wbase,  gB_h + boff0 + k0);
        gld16(sb + 12288 + wbase, gB_l + boff0 + k0);
    };

    auto compute = [&](int slot) {
        const u16* LA = lds + slot * SLOT;
        const u16* LB = LA + 8192;
        short8 afh[4], afl[4], bfh[2], bfl[2];
#pragma unroll
        for (int m = 0; m < 4; ++m) {
            int off = (wr * 64 + m * 16 + fr) * 32 + ps8;
            afh[m] = *(const short8*)(LA + off);
            afl[m] = *(const short8*)(LA + 4096 + off);
        }
#pragma unroll
        for (int n = 0; n < 2; ++n) {
            int off = (wc * 32 + n * 16 + fr) * 32 + ps8;
            bfh[n] = *(const short8*)(LB + off);
            bfl[n] = *(const short8*)(LB + 4096 + off);
        }
        __builtin_amdgcn_s_setprio(1);
#pragma unroll
        for (int m = 0; m < 4; ++m)
#pragma unroll
            for (int n = 0; n < 2; ++n) {
                acc[m][n] = __builtin_amdgcn_mfma_f32_16x16x32_bf16(afh[m], bfh[n], acc[m][n], 0, 0, 0);
                acc[m][n] = __builtin_amdgcn_mfma_f32_16x16x32_bf16(afh[m], bfl[n], acc[m][n], 0, 0, 0);
                acc[m][n] = __builtin_amdgcn_mfma_f32_16x16x32_bf16(afl[m], bfh[n], acc[m][n], 0, 0, 0);
            }
        __builtin_amdgcn_s_setprio(0);
    };

    stage(0, 0);
    int cs = 0;
    for (int h = 0; h < nsteps; ++h) {
        asm volatile("s_waitcnt vmcnt(0)" ::: "memory");
        __builtin_amdgcn_s_barrier();
        __builtin_amdgcn_sched_barrier(0);
        if (h + 1 < nsteps) stage(cs ^ 1, h + 1);
        compute(cs);
        cs ^= 1;
    }

    const int row0 = bi * 128 + wr * 64 + (lane >> 4) * 4;
    const int col0 = bj * 128 + wc * 32 + (lane & 15);
    float* o = S + (long)z * 2048 * 2048;
#pragma unroll
    for (int m = 0; m < 4; ++m)
#pragma unroll
        for (int n = 0; n < 2; ++n)
#pragma unroll
            for (int j = 0; j < 4; ++j)
                o[(long)(row0 + m * 16 + j) * 2048 + col0 + n * 16] = acc[m][n][j];
}

// =====================================================================
// softmax_k: per row i of S: read j<=i, scale 1/32, exp-normalize,
// write P hi/lo bf16 only for cols < ((i>>7)+1)*128 (all PV reads).
// =====================================================================
__global__ void softmax_k(const float* __restrict__ S, u16* __restrict__ Ph,
                          u16* __restrict__ Pl) {
    const long row = blockIdx.x;  // 0..8191
    const int i = (int)(row & 2047);
    const float* srow = S + row * 2048;
    u16* ph = Ph + row * 2048;
    u16* pl = Pl + row * 2048;
    const int t = threadIdx.x;
    const int limit = ((i >> 7) + 1) << 7;

    float v[8];
    float m = -1e30f;
#pragma unroll
    for (int j = 0; j < 8; ++j) {
        int c = j * 256 + t;
        float x = (c <= i) ? srow[c] : -1e30f;
        v[j] = x;
        m = fmaxf(m, x);
    }
#pragma unroll
    for (int off = 32; off; off >>= 1) m = fmaxf(m, __shfl_xor(m, off));
    __shared__ float redm[4], reds[4];
    if ((t & 63) == 0) redm[t >> 6] = m;
    __syncthreads();
    m = fmaxf(fmaxf(redm[0], redm[1]), fmaxf(redm[2], redm[3]));

    float p[8];
    float s = 0.f;
#pragma unroll
    for (int j = 0; j < 8; ++j) {
        int c = j * 256 + t;
        float e = (c <= i) ? __expf((v[j] - m) * 0.03125f) : 0.f;
        p[j] = e;
        s += e;
    }
#pragma unroll
    for (int off = 32; off; off >>= 1) s += __shfl_xor(s, off);
    if ((t & 63) == 0) reds[t >> 6] = s;
    __syncthreads();
    s = reds[0] + reds[1] + reds[2] + reds[3];
    const float inv = 1.f / s;
#pragma unroll
    for (int j = 0; j < 8; ++j) {
        int c = j * 256 + t;
        if (c < limit) {
            float o = p[j] * inv;
            u16 h = f2bf(o);
            ph[c] = h;
            pl[c] = f2bf(o - bf2f(h));
        }
    }
}

// =====================================================================
// pv_k: out = P * Vt^T per batch (P staged via gld16, R5-exact).
// Tile 128x128, K limited to (bi+1)*4 steps, bi reversed (LPT), ring-2.
// =====================================================================
__launch_bounds__(512, 2)
__global__ void pv_k(const u16* __restrict__ Ph, const u16* __restrict__ Pl,
                     const u16* __restrict__ Vth, const u16* __restrict__ Vtl,
                     float* __restrict__ out) {
    constexpr int SLOT = 16384;
    __shared__ u16 lds[2 * SLOT];

    const int bi = 15 - (int)blockIdx.x;  // LPT: longest K first
    const int bj = blockIdx.y, z = blockIdx.z;
    const int nsteps = (bi + 1) * 4;

    const u16* gA_h = Ph + (long)z * 2048 * 2048;
    const u16* gA_l = Pl + (long)z * 2048 * 2048;
    const u16* gB_h = Vth + (long)z * 1024 * 2048;
    const u16* gB_l = Vtl + (long)z * 1024 * 2048;

    const int tid = threadIdx.x;
    const int lane = tid & 63, w = tid >> 6;
    const int wr = w >> 2, wc = w & 3;

    const int srow = tid >> 2;
    const int ls8 = (((tid & 3) ^ ((tid >> 3) & 3)) << 3);
    const long aoff  = ((long)bi * 128 + srow) * 2048 + ls8;
    const long boff0 = ((long)bj * 128 + srow) * 2048 + ls8;
    const int wbase = w * 512;

    f32x4 acc[4][2] = {};
    const int fr = lane & 15;
    const int ps8 = (((lane >> 4) ^ ((fr >> 1) & 3)) << 3);

    auto stage = [&](int slot, int step) {
        const int k0 = step * 32;
        u16* sb = lds + slot * SLOT;
        gld16(sb + wbase,         gA_h + aoff + k0);
        gld16(sb + 4096 + wbase,  gA_l + aoff + k0);
        gld16(sb + 8192 + wbase,  gB_h + boff0 + k0);
        gld16(sb + 12288 + wbase, gB_l + boff0 + k0);
    };

    auto compute = [&](int slot) {
        const u16* LA = lds + slot * SLOT;
        const u16* LB = LA + 8192;
        short8 afh[4], afl[4], bfh[2], bfl[2];
#pragma unroll
        for (int m = 0; m < 4; ++m) {
            int off = (wr * 64 + m * 16 + fr) * 32 + ps8;
            afh[m] = *(const short8*)(LA + off);
            afl[m] = *(const short8*)(LA + 4096 + off);
        }
#pragma unroll
        for (int n = 0; n < 2; ++n) {
            int off = (wc * 32 + n * 16 + fr) * 32 + ps8;
            bfh[n] = *(const short8*)(LB + off);
            bfl[n] = *(const short8*)(LB + 4096 + off);
        }
        __builtin_amdgcn_s_setprio(1);
#pragma unroll
        for (int m = 0; m < 4; ++m)
#pragma unroll
            for (int n = 0; n < 2; ++n) {
                acc[m][n] = __builtin_amdgcn_mfma_f32_16x16x32_bf16(afh[m], bfh[n], acc[m][n], 0, 0, 0);
                acc[m][n] = __builtin_amdgcn_mfma_f32_16x16x32_bf16(afh[m], bfl[n], acc[m][n], 0, 0, 0);
                acc[m][n] = __builtin_amdgcn_mfma_f32_16x16x32_bf16(afl[m], bfh[n], acc[m][n], 0, 0, 0);
            }
        __builtin_amdgcn_s_setprio(0);
    };

    stage(0, 0);
    int cs = 0;
    for (int h = 0; h < nsteps; ++h) {
        asm volatile("s_waitcnt vmcnt(0)" ::: "memory");
        __builtin_amdgcn_s_barrier();
        __builtin_amdgcn_sched_barrier(0);
        if (h + 1 < nsteps) stage(cs ^ 1, h + 1);
        compute(cs);
        cs ^= 1;
    }

    const int row0 = bi * 128 + wr * 64 + (lane >> 4) * 4;
    const int col0 = bj * 128 + wc * 32 + (lane & 15);
    float* o = out + (long)z * 2048 * 1024;
#pragma unroll
    for (int m = 0; m < 4; ++m)
#pragma unroll
        for (int n = 0; n < 2; ++n)
#pragma unroll
            for (int j = 0; j < 4; ++j)
                o[(long)(row0 + m * 16 + j) * 1024 + col0 + n * 16] = acc[m][n][j];
}

// =====================================================================
extern "C" void kernel_launch(void* const* d_in, const int* in_sizes, int n_in,
                              void* d_out, int out_size, void* d_ws, size_t ws_size,
                              hipStream_t stream) {
    const float* x  = (const float*)d_in[0];
    const float* Wq = (const float*)d_in[1];
    const float* bq = (const float*)d_in[2];
    const float* Wk = (const float*)d_in[3];
    const float* bk = (const float*)d_in[4];
    const float* Wv = (const float*)d_in[5];
    const float* bv = (const float*)d_in[6];
    float* out = (float*)d_out;
    char* ws = (char*)d_ws;
    const size_t MB = 1ull << 20;

    // region1 (64MB): [xs_hi xs_lo wt_hi wt_lo] during proj, then S
    u16* xs_hi = (u16*)(ws + 0 * MB);
    u16* xs_lo = (u16*)(ws + 16 * MB);
    u16* wt_hi = (u16*)(ws + 32 * MB);
    u16* wt_lo = (u16*)(ws + 38 * MB);
    float* S   = (float*)(ws + 0 * MB);  // 64MB, after proj complete
    // region2 (64MB): [q_hi q_lo k_hi k_lo] during qk, then [P_hi P_lo]
    u16* q_hi = (u16*)(ws + 64 * MB);
    u16* q_lo = (u16*)(ws + 80 * MB);
    u16* k_hi = (u16*)(ws + 96 * MB);
    u16* k_lo = (u16*)(ws + 112 * MB);
    u16* P_hi = (u16*)(ws + 64 * MB);  // 32MB, after qk complete
    u16* P_lo = (u16*)(ws + 96 * MB);  // 32MB
    // region3/4
    u16* v_hi  = (u16*)(ws + 128 * MB);
    u16* v_lo  = (u16*)(ws + 144 * MB);
    u16* vt_hi = (u16*)(ws + 160 * MB);
    u16* vt_lo = (u16*)(ws + 176 * MB);

    const long WZ = 1024L * 1024;

    // 1) split x into bf16 hi/lo
    split_x_k<<<8192, 256, 0, stream>>>(x, xs_hi, xs_lo);
    // 2) transpose+split W -> Wt hi/lo ([3][1024][1024])
    splitT_w_k<<<dim3(32, 32, 3), dim3(32, 8), 0, stream>>>(Wq, Wk, Wv, wt_hi, wt_lo);
    // 3) QKV projections: 3 dispatches (~55us each) for per-phase observability
    proj_k<<<dim3(64, 4), 512, 0, stream>>>(xs_hi, xs_lo, wt_hi,          wt_lo,          q_hi, q_lo, bq);
    proj_k<<<dim3(64, 4), 512, 0, stream>>>(xs_hi, xs_lo, wt_hi + WZ,     wt_lo + WZ,     k_hi, k_lo, bk);
    proj_k<<<dim3(64, 4), 512, 0, stream>>>(xs_hi, xs_lo, wt_hi + 2 * WZ, wt_lo + 2 * WZ, v_hi, v_lo, bv);
    // 4) transpose V per batch -> vt [1024][2048]
    transpose_v_k<<<dim3(32, 64, 4), dim3(32, 8), 0, stream>>>(v_hi, v_lo, vt_hi, vt_lo);
    // 5) scores S = Q*K^T, causal block-skip (R5-exact, no swizzle)
    qk_k<<<dim3(16, 16, 4), 512, 0, stream>>>(q_hi, q_lo, k_hi, k_lo, S);
    // 6) causal softmax rows -> P hi/lo bf16
    softmax_k<<<8192, 256, 0, stream>>>(S, P_hi, P_lo);
    // 7) out = P * V, K-limited, LPT order
    pv_k<<<dim3(16, 8, 4), 512, 0, stream>>>(P_hi, P_lo, vt_hi, vt_lo, out);
}

// Round 9
// 408.794 us; speedup vs baseline: 1.1951x; 1.1258x over previous
//
#include <hip/hip_runtime.h>

typedef unsigned short u16;
typedef unsigned int u32;
typedef __attribute__((ext_vector_type(8))) short short8;
typedef __attribute__((ext_vector_type(4))) float f32x4;

// ---------- bf16 helpers (RNE) ----------
__device__ __forceinline__ u16 f2bf(float f) {
    u32 u = __float_as_uint(f);
    u32 r = (u + 0x7fffu + ((u >> 16) & 1u)) >> 16;
    return (u16)r;
}
__device__ __forceinline__ float bf2f(u16 h) {
    return __uint_as_float(((u32)h) << 16);
}

// ---------- async global->LDS, 16B per lane (dst = wave-uniform base + lane*16) ----------
__device__ __forceinline__ void gld16(u16* lds_dst, const u16* g_src) {
    __builtin_amdgcn_global_load_lds(
        (const __attribute__((address_space(1))) unsigned int*)g_src,
        (__attribute__((address_space(3))) unsigned int*)lds_dst,
        16, 0, 0);
}

// =====================================================================
// split_x: fp32 [8192*1024] -> bf16 hi/lo
// =====================================================================
__global__ void split_x_k(const float* __restrict__ x, u16* __restrict__ xh,
                          u16* __restrict__ xl) {
    long i = ((long)blockIdx.x * 256 + threadIdx.x) * 4;
    float4 f = *(const float4*)(x + i);
    u16 h0 = f2bf(f.x), h1 = f2bf(f.y), h2 = f2bf(f.z), h3 = f2bf(f.w);
    u16 l0 = f2bf(f.x - bf2f(h0)), l1 = f2bf(f.y - bf2f(h1));
    u16 l2 = f2bf(f.z - bf2f(h2)), l3 = f2bf(f.w - bf2f(h3));
    uint2 hv, lv;
    hv.x = (u32)h0 | ((u32)h1 << 16); hv.y = (u32)h2 | ((u32)h3 << 16);
    lv.x = (u32)l0 | ((u32)l1 << 16); lv.y = (u32)l2 | ((u32)l3 << 16);
    *(uint2*)(xh + i) = hv;
    *(uint2*)(xl + i) = lv;
}

// =====================================================================
// splitT_w: W[k][n] fp32 (1024x1024, z in 0..2) -> Wt[n][k] bf16 hi/lo
// =====================================================================
__global__ void splitT_w_k(const float* __restrict__ Wq, const float* __restrict__ Wk,
                           const float* __restrict__ Wv, u16* __restrict__ wth,
                           u16* __restrict__ wtl) {
    __shared__ float tile[32][33];
    int z = blockIdx.z;
    const float* W = (z == 0) ? Wq : (z == 1) ? Wk : Wv;
    int n0 = blockIdx.x * 32, k0 = blockIdx.y * 32;
    int tx = threadIdx.x, ty = threadIdx.y;
#pragma unroll
    for (int r0 = 0; r0 < 4; ++r0) {
        int r = ty + r0 * 8;
        tile[r][tx] = W[(long)(k0 + r) * 1024 + n0 + tx];
    }
    __syncthreads();
    long zoff = (long)z * 1024 * 1024;
#pragma unroll
    for (int r0 = 0; r0 < 4; ++r0) {
        int r = ty + r0 * 8;
        float f = tile[tx][r];
        u16 h = f2bf(f), l = f2bf(f - bf2f(h));
        long idx = zoff + (long)(n0 + r) * 1024 + k0 + tx;
        wth[idx] = h;
        wtl[idx] = l;
    }
}

// =====================================================================
// transpose_v: v hi/lo [B*2048][1024] -> vt hi/lo per-batch [1024][2048]
// =====================================================================
__global__ void transpose_v_k(const u16* __restrict__ vh, const u16* __restrict__ vl,
                              u16* __restrict__ vth, u16* __restrict__ vtl) {
    __shared__ u16 th[32][33];
    __shared__ u16 tl[32][33];
    int z = blockIdx.z;
    int d0 = blockIdx.x * 32, s0 = blockIdx.y * 32;
    int tx = threadIdx.x, ty = threadIdx.y;
#pragma unroll
    for (int r0 = 0; r0 < 4; ++r0) {
        int r = ty + r0 * 8;
        long idx = ((long)z * 2048 + s0 + r) * 1024 + d0 + tx;
        th[r][tx] = vh[idx];
        tl[r][tx] = vl[idx];
    }
    __syncthreads();
    long zoff = (long)z * 1024 * 2048;
#pragma unroll
    for (int r0 = 0; r0 < 4; ++r0) {
        int r = ty + r0 * 8;
        long idx = zoff + (long)(d0 + r) * 2048 + s0 + tx;
        vth[idx] = th[tx][r];
        vtl[idx] = tl[tx][r];
    }
}

// =====================================================================
// proj_k: all 3 projections in ONE dispatch (grid z selects q/k/v) —
// byte-identical body to the R2/R5 161-us config. C = A*B^T 3-term
// split, 8 waves, tile 128x256, BK=32, ring-3 LDS, depth-2 prefetch,
// counted vmcnt(6), XOR swizzle.
// =====================================================================
__launch_bounds__(512, 2)
__global__ void proj_k(const u16* __restrict__ Ah, const u16* __restrict__ Al,
                       const u16* __restrict__ Bh, const u16* __restrict__ Bl,
                       u16* __restrict__ oh0, u16* __restrict__ oh1, u16* __restrict__ oh2,
                       u16* __restrict__ ol0, u16* __restrict__ ol1, u16* __restrict__ ol2,
                       const float* __restrict__ b0, const float* __restrict__ b1,
                       const float* __restrict__ b2) {
    constexpr int NF = 4;
    constexpr int BN = 256;
    constexpr int SLOT = 8192 + NF * 4096;
    __shared__ u16 lds[3 * SLOT];

    const int bi = blockIdx.x, bj = blockIdx.y, z = blockIdx.z;
    const int nsteps = 32;

    const u16* gA_h = Ah;
    const u16* gA_l = Al;
    const u16* gB_h = Bh + (long)z * 1024 * 1024;
    const u16* gB_l = Bl + (long)z * 1024 * 1024;

    const int tid = threadIdx.x;
    const int lane = tid & 63, w = tid >> 6;
    const int wr = w >> 2, wc = w & 3;

    const int srow = tid >> 2;
    const int ls8 = (((tid & 3) ^ ((tid >> 3) & 3)) << 3);
    const long aoff  = ((long)bi * 128 + srow) * 1024 + ls8;
    const long boff0 = ((long)bj * BN + srow) * 1024 + ls8;
    const long boff1 = boff0 + 128L * 1024;
    const int wbase = w * 512;

    f32x4 acc[4][NF] = {};

    const int fr = lane & 15;
    const int ps8 = (((lane >> 4) ^ ((fr >> 1) & 3)) << 3);

    auto stage = [&](int slot, int step) {
        const int k0 = step * 32;
        u16* sb = lds + slot * SLOT;
        gld16(sb + wbase,               gA_h + aoff + k0);
        gld16(sb + 4096 + wbase,        gA_l + aoff + k0);
        gld16(sb + 8192 + wbase,        gB_h + boff0 + k0);
        gld16(sb + 12288 + wbase,       gB_h + boff1 + k0);
        gld16(sb + 16384 + wbase,       gB_l + boff0 + k0);
        gld16(sb + 20480 + wbase,       gB_l + boff1 + k0);
    };

    auto compute = [&](int slot) {
        const u16* LA = lds + slot * SLOT;
        const u16* LB = LA + 8192;
        short8 afh[4], afl[4], bfh[NF], bfl[NF];
#pragma unroll
        for (int m = 0; m < 4; ++m) {
            int off = (wr * 64 + m * 16 + fr) * 32 + ps8;
            afh[m] = *(const short8*)(LA + off);
            afl[m] = *(const short8*)(LA + 4096 + off);
        }
#pragma unroll
        for (int n = 0; n < NF; ++n) {
            int off = (wc * (NF * 16) + n * 16 + fr) * 32 + ps8;
            bfh[n] = *(const short8*)(LB + off);
            bfl[n] = *(const short8*)(LB + NF * 2048 + off);
        }
        __builtin_amdgcn_s_setprio(1);
#pragma unroll
        for (int m = 0; m < 4; ++m)
#pragma unroll
            for (int n = 0; n < NF; ++n) {
                acc[m][n] = __builtin_amdgcn_mfma_f32_16x16x32_bf16(afh[m], bfh[n], acc[m][n], 0, 0, 0);
                acc[m][n] = __builtin_amdgcn_mfma_f32_16x16x32_bf16(afh[m], bfl[n], acc[m][n], 0, 0, 0);
                acc[m][n] = __builtin_amdgcn_mfma_f32_16x16x32_bf16(afl[m], bfh[n], acc[m][n], 0, 0, 0);
            }
        __builtin_amdgcn_s_setprio(0);
    };

    stage(0, 0);
    stage(1, 1);
    int cs = 0, ns = 2;
    for (int h = 0; h < nsteps; ++h) {
        if (h + 1 < nsteps) {
            asm volatile("s_waitcnt vmcnt(6)" ::: "memory");
        } else {
            asm volatile("s_waitcnt vmcnt(0)" ::: "memory");
        }
        __builtin_amdgcn_s_barrier();
        __builtin_amdgcn_sched_barrier(0);
        if (h + 2 < nsteps) stage(ns, h + 2);
        compute(cs);
        cs = (cs == 2) ? 0 : cs + 1;
        ns = (ns == 2) ? 0 : ns + 1;
    }

    const int row0 = bi * 128 + wr * 64 + (lane >> 4) * 4;
    const int col0 = bj * BN + wc * (NF * 16) + (lane & 15);

    const float* bias = (z == 0) ? b0 : (z == 1) ? b1 : b2;
    u16* oh = (z == 0) ? oh0 : (z == 1) ? oh1 : oh2;
    u16* ol = (z == 0) ? ol0 : (z == 1) ? ol1 : ol2;
#pragma unroll
    for (int n = 0; n < NF; ++n) {
        float bv = bias[col0 + n * 16];
#pragma unroll
        for (int m = 0; m < 4; ++m)
#pragma unroll
            for (int j = 0; j < 4; ++j) {
                float v = acc[m][n][j] + bv;
                long idx = (long)(row0 + m * 16 + j) * 1024 + col0 + n * 16;
                u16 h = f2bf(v);
                oh[idx] = h;
                ol[idx] = f2bf(v - bf2f(h));
            }
    }
}

// =====================================================================
// qk_k: S = Q * K^T per batch, causal block-skip. Tile 128x128, ring-2
// LDS (2 blocks/CU), depth-1 prefetch. 1-D grid 1024 with balanced
// bi-pairing XCD swizzle: XCD c (= bid%8 round-robin) gets groups with
// bi in {c, 15-c} (68 surviving blocks per XCD, equal work) and all bj
// of a (bi,z) group co-XCD (Q panel L2 reuse).
// =====================================================================
__launch_bounds__(512, 2)
__global__ void qk_k(const u16* __restrict__ Qh, const u16* __restrict__ Ql,
                     const u16* __restrict__ Kh, const u16* __restrict__ Kl,
                     float* __restrict__ S) {
    constexpr int SLOT = 16384;  // A hi/lo + B hi/lo, each [128][32]
    __shared__ u16 lds[2 * SLOT];

    const int bid = blockIdx.x;                       // 0..1023
    const int logical = (bid & 7) * 128 + (bid >> 3); // XCD c owns logicals [c*128,(c+1)*128)
    const int bj = logical & 15;
    const int gidx = logical >> 4;                    // 0..63, c = gidx>>3
    const int c = gidx >> 3, j = gidx & 7;
    const int bi = (j < 4) ? c : 15 - c;              // pairing: {c, 15-c}
    const int z = j & 3;
    if (bj > bi) return;
    const int nsteps = 32;

    const u16* gA_h = Qh + (long)z * 2048 * 1024;
    const u16* gA_l = Ql + (long)z * 2048 * 1024;
    const u16* gB_h = Kh + (long)z * 2048 * 1024;
    const u16* gB_l = Kl + (long)z * 2048 * 1024;

    const int tid = threadIdx.x;
    const int lane = tid & 63, w = tid >> 6;
    const int wr = w >> 2, wc = w & 3;

    const int srow = tid >> 2;
    const int ls8 = (((tid & 3) ^ ((tid >> 3) & 3)) << 3);
    const long aoff  = ((long)bi * 128 + srow) * 1024 + ls8;
    const long boff0 = ((long)bj * 128 + srow) * 1024 + ls8;
    const int wbase = w * 512;

    f32x4 acc[4][2] = {};
    const int fr = lane & 15;
    const int ps8 = (((lane >> 4) ^ ((fr >> 1) & 3)) << 3);

    auto stage = [&](int slot, int step) {
        const int k0 = step * 32;
        u16* sb = lds + slot * SLOT;
        gld16(sb + wbase,         gA_h + aoff + k0);
        gld16(sb + 4096 + wbase,  gA_l + aoff + k0);
        gld16(sb + 8192 + wbase,  gB_h + boff0 + k0);
        gld16(sb + 12288 + wbase, gB_l + boff0 + k0);
    };

    auto compute = [&](int slot) {
        const u16* LA = lds + slot * SLOT;
        const u16* LB = LA + 8192;
        short8 afh[4], afl[4], bfh[2], bfl[2];
#pragma unroll
        for (int m = 0; m < 4; ++m) {
            int off = (wr * 64 + m * 16 + fr) * 32 + ps8;
            afh[m] = *(const short8*)(LA + off);
            afl[m] = *(const short8*)(LA + 4096 + off);
        }
#pragma unroll
        for (int n = 0; n < 2; ++n) {
            int off = (wc * 32 + n * 16 + fr) * 32 + ps8;
            bfh[n] = *(const short8*)(LB + off);
            bfl[n] = *(const short8*)(LB + 4096 + off);
        }
        __builtin_amdgcn_s_setprio(1);
#pragma unroll
        for (int m = 0; m < 4; ++m)
#pragma unroll
            for (int n = 0; n < 2; ++n) {
                acc[m][n] = __builtin_amdgcn_mfma_f32_16x16x32_bf16(afh[m], bfh[n], acc[m][n], 0, 0, 0);
                acc[m][n] = __builtin_amdgcn_mfma_f32_16x16x32_bf16(afh[m], bfl[n], acc[m][n], 0, 0, 0);
                acc[m][n] = __builtin_amdgcn_mfma_f32_16x16x32_bf16(afl[m], bfh[n], acc[m][n], 0, 0, 0);
            }
        __builtin_amdgcn_s_setprio(0);
    };

    stage(0, 0);
    int cs = 0;
    for (int h = 0; h < nsteps; ++h) {
        asm volatile("s_waitcnt vmcnt(0)" ::: "memory");
        __builtin_amdgcn_s_barrier();
        __builtin_amdgcn_sched_barrier(0);
        if (h + 1 < nsteps) stage(cs ^ 1, h + 1);
        compute(cs);
        cs ^= 1;
    }

    const int row0 = bi * 128 + wr * 64 + (lane >> 4) * 4;
    const int col0 = bj * 128 + wc * 32 + (lane & 15);
    float* o = S + (long)z * 2048 * 2048;
#pragma unroll
    for (int m = 0; m < 4; ++m)
#pragma unroll
        for (int n = 0; n < 2; ++n)
#pragma unroll
            for (int j = 0; j < 4; ++j)
                o[(long)(row0 + m * 16 + j) * 2048 + col0 + n * 16] = acc[m][n][j];
}

// =====================================================================
// softmax_k: per row i of S: read j<=i, scale 1/32, exp-normalize,
// write P hi/lo bf16 only for cols < ((i>>7)+1)*128 (all PV reads).
// =====================================================================
__global__ void softmax_k(const float* __restrict__ S, u16* __restrict__ Ph,
                          u16* __restrict__ Pl) {
    const long row = blockIdx.x;  // 0..8191
    const int i = (int)(row & 2047);
    const float* srow = S + row * 2048;
    u16* ph = Ph + row * 2048;
    u16* pl = Pl + row * 2048;
    const int t = threadIdx.x;
    const int limit = ((i >> 7) + 1) << 7;

    float v[8];
    float m = -1e30f;
#pragma unroll
    for (int j = 0; j < 8; ++j) {
        int c = j * 256 + t;
        float x = (c <= i) ? srow[c] : -1e30f;
        v[j] = x;
        m = fmaxf(m, x);
    }
#pragma unroll
    for (int off = 32; off; off >>= 1) m = fmaxf(m, __shfl_xor(m, off));
    __shared__ float redm[4], reds[4];
    if ((t & 63) == 0) redm[t >> 6] = m;
    __syncthreads();
    m = fmaxf(fmaxf(redm[0], redm[1]), fmaxf(redm[2], redm[3]));

    float p[8];
    float s = 0.f;
#pragma unroll
    for (int j = 0; j < 8; ++j) {
        int c = j * 256 + t;
        float e = (c <= i) ? __expf((v[j] - m) * 0.03125f) : 0.f;
        p[j] = e;
        s += e;
    }
#pragma unroll
    for (int off = 32; off; off >>= 1) s += __shfl_xor(s, off);
    if ((t & 63) == 0) reds[t >> 6] = s;
    __syncthreads();
    s = reds[0] + reds[1] + reds[2] + reds[3];
    const float inv = 1.f / s;
#pragma unroll
    for (int j = 0; j < 8; ++j) {
        int c = j * 256 + t;
        if (c < limit) {
            float o = p[j] * inv;
            u16 h = f2bf(o);
            ph[c] = h;
            pl[c] = f2bf(o - bf2f(h));
        }
    }
}

// =====================================================================
// pv_k: out = P * Vt^T per batch (P staged via gld16). Tile 128x128,
// K limited to (bi+1)*4 steps, ring-2 (2 blocks/CU). 1-D grid 512 with
// balanced bi-pairing XCD swizzle: XCD c gets bi in {c, 15-c} (equal 17
// work-units x 4z) and all 8 bj of a (bi,z) group co-XCD, so each P
// panel is fetched by one XCD only (working set 4.25MB/XCD).
// =====================================================================
__launch_bounds__(512, 2)
__global__ void pv_k(const u16* __restrict__ Ph, const u16* __restrict__ Pl,
                     const u16* __restrict__ Vth, const u16* __restrict__ Vtl,
                     float* __restrict__ out) {
    constexpr int SLOT = 16384;
    __shared__ u16 lds[2 * SLOT];

    const int bid = blockIdx.x;                      // 0..511
    const int logical = (bid & 7) * 64 + (bid >> 3); // XCD c owns logicals [c*64,(c+1)*64)
    const int bj = logical & 7;
    const int gidx = logical >> 3;                   // 0..63, c = gidx>>3
    const int c = gidx >> 3, j = gidx & 7;
    const int bi = (j < 4) ? c : 15 - c;             // pairing: {c, 15-c}
    const int z = j & 3;
    const int nsteps = (bi + 1) * 4;

    const u16* gA_h = Ph + (long)z * 2048 * 2048;
    const u16* gA_l = Pl + (long)z * 2048 * 2048;
    const u16* gB_h = Vth + (long)z * 1024 * 2048;
    const u16* gB_l = Vtl + (long)z * 1024 * 2048;

    const int tid = threadIdx.x;
    const int lane = tid & 63, w = tid >> 6;
    const int wr = w >> 2, wc = w & 3;

    const int srow = tid >> 2;
    const int ls8 = (((tid & 3) ^ ((tid >> 3) & 3)) << 3);
    const long aoff  = ((long)bi * 128 + srow) * 2048 + ls8;
    const long boff0 = ((long)bj * 128 + srow) * 2048 + ls8;
    const int wbase = w * 512;

    f32x4 acc[4][2] = {};
    const int fr = lane & 15;
    const int ps8 = (((lane >> 4) ^ ((fr >> 1) & 3)) << 3);

    auto stage = [&](int slot, int step) {
        const int k0 = step * 32;
        u16* sb = lds + slot * SLOT;
        gld16(sb + wbase,         gA_h + aoff + k0);
        gld16(sb + 4096 + wbase,  gA_l + aoff + k0);
        gld16(sb + 8192 + wbase,  gB_h + boff0 + k0);
        gld16(sb + 12288 + wbase, gB_l + boff0 + k0);
    };

    auto compute = [&](int slot) {
        const u16* LA = lds + slot * SLOT;
        const u16* LB = LA + 8192;
        short8 afh[4], afl[4], bfh[2], bfl[2];
#pragma unroll
        for (int m = 0; m < 4; ++m) {
            int off = (wr * 64 + m * 16 + fr) * 32 + ps8;
            afh[m] = *(const short8*)(LA + off);
            afl[m] = *(const short8*)(LA + 4096 + off);
        }
#pragma unroll
        for (int n = 0; n < 2; ++n) {
            int off = (wc * 32 + n * 16 + fr) * 32 + ps8;
            bfh[n] = *(const short8*)(LB + off);
            bfl[n] = *(const short8*)(LB + 4096 + off);
        }
        __builtin_amdgcn_s_setprio(1);
#pragma unroll
        for (int m = 0; m < 4; ++m)
#pragma unroll
            for (int n = 0; n < 2; ++n) {
                acc[m][n] = __builtin_amdgcn_mfma_f32_16x16x32_bf16(afh[m], bfh[n], acc[m][n], 0, 0, 0);
                acc[m][n] = __builtin_amdgcn_mfma_f32_16x16x32_bf16(afh[m], bfl[n], acc[m][n], 0, 0, 0);
                acc[m][n] = __builtin_amdgcn_mfma_f32_16x16x32_bf16(afl[m], bfh[n], acc[m][n], 0, 0, 0);
            }
        __builtin_amdgcn_s_setprio(0);
    };

    stage(0, 0);
    int cs = 0;
    for (int h = 0; h < nsteps; ++h) {
        asm volatile("s_waitcnt vmcnt(0)" ::: "memory");
        __builtin_amdgcn_s_barrier();
        __builtin_amdgcn_sched_barrier(0);
        if (h + 1 < nsteps) stage(cs ^ 1, h + 1);
        compute(cs);
        cs ^= 1;
    }

    const int row0 = bi * 128 + wr * 64 + (lane >> 4) * 4;
    const int col0 = bj * 128 + wc * 32 + (lane & 15);
    float* o = out + (long)z * 2048 * 1024;
#pragma unroll
    for (int m = 0; m < 4; ++m)
#pragma unroll
        for (int n = 0; n < 2; ++n)
#pragma unroll
            for (int j = 0; j < 4; ++j)
                o[(long)(row0 + m * 16 + j) * 1024 + col0 + n * 16] = acc[m][n][j];
}

// =====================================================================
extern "C" void kernel_launch(void* const* d_in, const int* in_sizes, int n_in,
                              void* d_out, int out_size, void* d_ws, size_t ws_size,
                              hipStream_t stream) {
    const float* x  = (const float*)d_in[0];
    const float* Wq = (const float*)d_in[1];
    const float* bq = (const float*)d_in[2];
    const float* Wk = (const float*)d_in[3];
    const float* bk = (const float*)d_in[4];
    const float* Wv = (const float*)d_in[5];
    const float* bv = (const float*)d_in[6];
    float* out = (float*)d_out;
    char* ws = (char*)d_ws;
    const size_t MB = 1ull << 20;

    // region1 (64MB): [xs_hi xs_lo wt_hi wt_lo] during proj, then S
    u16* xs_hi = (u16*)(ws + 0 * MB);
    u16* xs_lo = (u16*)(ws + 16 * MB);
    u16* wt_hi = (u16*)(ws + 32 * MB);
    u16* wt_lo = (u16*)(ws + 38 * MB);
    float* S   = (float*)(ws + 0 * MB);  // 64MB, after proj complete
    // region2 (64MB): [q_hi q_lo k_hi k_lo] during qk, then [P_hi P_lo]
    u16* q_hi = (u16*)(ws + 64 * MB);
    u16* q_lo = (u16*)(ws + 80 * MB);
    u16* k_hi = (u16*)(ws + 96 * MB);
    u16* k_lo = (u16*)(ws + 112 * MB);
    u16* P_hi = (u16*)(ws + 64 * MB);  // 32MB, after qk complete
    u16* P_lo = (u16*)(ws + 96 * MB);  // 32MB
    // region3/4
    u16* v_hi  = (u16*)(ws + 128 * MB);
    u16* v_lo  = (u16*)(ws + 144 * MB);
    u16* vt_hi = (u16*)(ws + 160 * MB);
    u16* vt_lo = (u16*)(ws + 176 * MB);

    // 1) split x into bf16 hi/lo
    split_x_k<<<8192, 256, 0, stream>>>(x, xs_hi, xs_lo);
    // 2) transpose+split W -> Wt hi/lo ([3][1024][1024])
    splitT_w_k<<<dim3(32, 32, 3), dim3(32, 8), 0, stream>>>(Wq, Wk, Wv, wt_hi, wt_lo);
    // 3) QKV projections (merged, grid z=3; R2/R5-proven 161us config)
    proj_k<<<dim3(64, 4, 3), 512, 0, stream>>>(
        xs_hi, xs_lo, wt_hi, wt_lo, q_hi, k_hi, v_hi, q_lo, k_lo, v_lo, bq, bk, bv);
    // 4) transpose V per batch -> vt [1024][2048]
    transpose_v_k<<<dim3(32, 64, 4), dim3(32, 8), 0, stream>>>(v_hi, v_lo, vt_hi, vt_lo);
    // 5) scores S = Q*K^T, causal block-skip, balanced XCD swizzle
    qk_k<<<1024, 512, 0, stream>>>(q_hi, q_lo, k_hi, k_lo, S);
    // 6) causal softmax rows -> P hi/lo bf16
    softmax_k<<<8192, 256, 0, stream>>>(S, P_hi, P_lo);
    // 7) out = P * V, K-limited, balanced XCD swizzle
    pv_k<<<512, 512, 0, stream>>>(P_hi, P_lo, vt_hi, vt_lo, out);
}